// Round 1
// baseline (19859.676 us; speedup 1.0000x reference)
//
#include <hip/hip_runtime.h>

typedef unsigned short u16;
typedef _Float16 f16;
typedef f16 half8 __attribute__((ext_vector_type(8)));
typedef float float4v __attribute__((ext_vector_type(4)));
typedef unsigned uint2v __attribute__((ext_vector_type(2)));

union HV { uint4 u; half8 h; u16 s[8]; };

__device__ __forceinline__ float h2f(u16 u) { union { u16 u; f16 h; } c; c.u = u; return (float)c.h; }
__device__ __forceinline__ u16 f2h(float f) { union { u16 u; f16 h; } c; c.h = (f16)f; return c.u; }

// ---- coherent (cross-XCD) access helpers: sc0 sc1 => operate at LLC, bypass XCD L2 ----
// 128-bit vectors are NOT valid as "v" asm *inputs*; 64-bit scalars and vector
// *outputs* are fine.
__device__ __forceinline__ void store_coh_u16(u16* p, unsigned v) {
  asm volatile("global_store_short %0, %1, off sc0 sc1" :: "v"(p), "v"(v) : "memory");
}
__device__ __forceinline__ void store_coh_u32(void* p, unsigned v) {
  asm volatile("global_store_dword %0, %1, off sc0 sc1" :: "v"(p), "v"(v) : "memory");
}
// single-instruction 8B store: [f32 payload | u32 epoch] — atomically visible
__device__ __forceinline__ void store_coh_tag2(float* p, float val, unsigned tag) {
  unsigned long long pk = (unsigned long long)__float_as_uint(val) |
                          ((unsigned long long)tag << 32);
  asm volatile("global_store_dwordx2 %0, %1, off sc0 sc1" :: "v"(p), "v"(pk) : "memory");
}

// ---------------- fp32 -> fp16 convert ----------------
__global__ void cvt_f32_f16(const float* __restrict__ s, u16* __restrict__ d, int n) {
  for (int i = blockIdx.x * blockDim.x + threadIdx.x; i < n; i += gridDim.x * blockDim.x)
    d[i] = f2h(s[i]);
}

// ---------------- GEMM: C[M][2048] = A[M][K] * B[2048][K]^T (fp16 in/out, fp32 accum) ----------
__global__ __launch_bounds__(256) void gemm_f16(const u16* __restrict__ A, const u16* __restrict__ B,
                                                u16* __restrict__ C, int K) {
  __shared__ u16 As[128][40];
  __shared__ u16 Bs[128][40];
  const int tid = threadIdx.x, lane = tid & 63, wid = tid >> 6;
  const int col = lane & 15, quad = lane >> 4;
  const int wm = (wid & 1) * 64, wn = (wid >> 1) * 64;
  const int n0 = blockIdx.x * 128;
  const int m0 = blockIdx.y * 128;
  float4v acc[4][4];
  #pragma unroll
  for (int i = 0; i < 4; ++i)
    #pragma unroll
    for (int j = 0; j < 4; ++j) acc[i][j] = (float4v){0.f, 0.f, 0.f, 0.f};

  const int srow = tid >> 2;
  const int schunk = (tid & 3) * 8;

  for (int k0 = 0; k0 < K; k0 += 32) {
    __syncthreads();
    #pragma unroll
    for (int r2 = 0; r2 < 2; ++r2) {
      int row = srow + 64 * r2;
      int kk = k0 + schunk;
      uint4 av = {0, 0, 0, 0}, bv = {0, 0, 0, 0};
      if (kk + 8 <= K) {
        av = *(const uint4*)(A + (size_t)(m0 + row) * K + kk);
        bv = *(const uint4*)(B + (size_t)(n0 + row) * K + kk);
      }
      *(uint4*)&As[row][schunk] = av;
      *(uint4*)&Bs[row][schunk] = bv;
    }
    __syncthreads();
    HV af[4], bf[4];
    #pragma unroll
    for (int i = 0; i < 4; ++i) af[i].u = *(const uint4*)&As[wm + i * 16 + col][quad * 8];
    #pragma unroll
    for (int j = 0; j < 4; ++j) bf[j].u = *(const uint4*)&Bs[wn + j * 16 + col][quad * 8];
    #pragma unroll
    for (int i = 0; i < 4; ++i)
      #pragma unroll
      for (int j = 0; j < 4; ++j)
        acc[i][j] = __builtin_amdgcn_mfma_f32_16x16x32_f16(af[i].h, bf[j].h, acc[i][j], 0, 0, 0);
  }
  #pragma unroll
  for (int i = 0; i < 4; ++i)
    #pragma unroll
    for (int j = 0; j < 4; ++j)
      #pragma unroll
      for (int r = 0; r < 4; ++r) {
        int m = m0 + wm + i * 16 + quad * 4 + r;
        int n = n0 + wn + j * 16 + col;
        C[(size_t)m * 2048 + n] = f2h(acc[i][j][r]);
      }
}

// ---------------- BatchNorm stats over 32000 rows ----------------
__global__ void bn_stats(const u16* __restrict__ C, float* __restrict__ acc) {
  int c = blockIdx.x * 256 + threadIdx.x;
  int r0 = blockIdx.y * 256;
  float s = 0.f, q = 0.f;
  for (int r = r0; r < r0 + 256; ++r) {
    float v = h2f(C[(size_t)r * 2048 + c]);
    s += v; q += v * v;
  }
  atomicAdd(&acc[2 * c], s);
  atomicAdd(&acc[2 * c + 1], q);
}

__global__ void bn_final(const float* __restrict__ acc, const float* __restrict__ g,
                         const float* __restrict__ b, float2* __restrict__ ss) {
  int c = blockIdx.x * 256 + threadIdx.x;
  float mean = acc[2 * c] * (1.f / 32000.f);
  float var = acc[2 * c + 1] * (1.f / 32000.f) - mean * mean;
  float sc = g[c] * rsqrtf(var + 1e-5f);
  float2 o; o.x = sc; o.y = b[c] - mean * sc;
  ss[c] = o;
}

// ---------------- persistent recurrence ----------------
// 64 blocks x 256 threads (co-resident). Block beta owns h-cols [16b,16b+16).
//
// Per step, exactly TWO cross-block communication rounds (the minimum):
//   R1 (stats all-to-all): each block stores its per-batch LN partials as
//      epoch-tagged 8B records ([f32|tag] single dwordx2, atomically visible).
//      Readers poll-gather the DATA directly until every tag matches — no flag
//      barrier, no store-drain, no syncthreads.
//   R2 (h broadcast): h stores -> vmcnt(0) -> per-writer-wave epoch flag
//      (2 flags/block). All 4 waves poll all 64 blocks' flag pairs
//      independently (one dwordx2 per lane) — no syncthreads, no wave0
//      bottleneck.
//
// Safety notes:
//  - single-buffer hbuf is safe: a block passes the stats poll of step t only
//    after EVERY block's phase-A h load completed (load precedes stats store
//    in program order), so no step-t+1 h store can race a step-t h load.
//  - pstats slot (t&1) ABA-safe: writer reuses a slot only after passing the
//    h-flag poll twice; its own in-flight stores are drained by the
//    interleaved vmcnt(0)s every step.
//  - the single __syncthreads covers the LDS `red` hazard; kh==1's next-step
//    red write is ordered after kh==0's red read via the block's own h-flag.
//
// pstats layout: float pstats[2][32][64][4] : [phase][batch][block][s,tag,q,tag]
template <int OUT_F32>
__global__ __launch_bounds__(256, 1) void rec_kernel(
    const u16* __restrict__ w,      // [32*1000][2048] fp16 (pre-BN)
    const float2* __restrict__ ss,  // [2048] BN scale/shift
    const u16* __restrict__ U,      // [2048][1024] fp16
    u16* hbuf,                      // [32][1024] fp16 (current h, cross-block shared)
    float* pstats,                  // [2][32][64][4] tagged LN partial stats
    unsigned* flags,                // [64][16] u32: [block][writer-wave 0..1] epochs
    u16* out16, float* out32) {
  const int tid = threadIdx.x, lane = tid & 63, wid = tid >> 6;
  const int mh = wid & 1, kh = wid >> 1;
  const int beta = blockIdx.x;
  const int col = lane & 15, quad = lane >> 4;
  __shared__ float4v red[2][2][64];

  const int ja = beta * 16 + col;   // a gate col == h col owned by this lane
  const int jz = 1024 + ja;         // paired z gate col

  HV uf0[16], uf1[16];              // U fragments resident in registers
  #pragma unroll
  for (int kk = 0; kk < 16; ++kk) {
    int k = kh * 512 + kk * 32 + quad * 8;
    uf0[kk].u = *(const uint4*)(U + (size_t)ja * 1024 + k);
    uf1[kk].u = *(const uint4*)(U + (size_t)jz * 1024 + k);
  }
  float2 ssa = ss[ja], ssz = ss[jz];
  float hreg[4] = {0.f, 0.f, 0.f, 0.f};

  const int b0 = mh * 16 + quad * 4;             // batch group for phase-B lanes
  const u16* aptr = hbuf + (mh * 16 + col) * 1024 + kh * 512 + quad * 8;

  for (int t = 0; t < 1000; ++t) {
    const unsigned tag = (unsigned)t + 1u;
    // ---- phase A: uh = h @ U^T (coherent 16B loads of h; M=32, N=32, K split over kh) ----
    HV af[16];
    asm volatile(
        "global_load_dwordx4 %0,  %16, off sc0 sc1\n\t"
        "global_load_dwordx4 %1,  %16, off offset:64  sc0 sc1\n\t"
        "global_load_dwordx4 %2,  %16, off offset:128 sc0 sc1\n\t"
        "global_load_dwordx4 %3,  %16, off offset:192 sc0 sc1\n\t"
        "global_load_dwordx4 %4,  %16, off offset:256 sc0 sc1\n\t"
        "global_load_dwordx4 %5,  %16, off offset:320 sc0 sc1\n\t"
        "global_load_dwordx4 %6,  %16, off offset:384 sc0 sc1\n\t"
        "global_load_dwordx4 %7,  %16, off offset:448 sc0 sc1\n\t"
        "global_load_dwordx4 %8,  %16, off offset:512 sc0 sc1\n\t"
        "global_load_dwordx4 %9,  %16, off offset:576 sc0 sc1\n\t"
        "global_load_dwordx4 %10, %16, off offset:640 sc0 sc1\n\t"
        "global_load_dwordx4 %11, %16, off offset:704 sc0 sc1\n\t"
        "global_load_dwordx4 %12, %16, off offset:768 sc0 sc1\n\t"
        "global_load_dwordx4 %13, %16, off offset:832 sc0 sc1\n\t"
        "global_load_dwordx4 %14, %16, off offset:896 sc0 sc1\n\t"
        "global_load_dwordx4 %15, %16, off offset:960 sc0 sc1\n\t"
        "s_waitcnt vmcnt(0)"
        : "=v"(af[0].u), "=v"(af[1].u), "=v"(af[2].u), "=v"(af[3].u),
          "=v"(af[4].u), "=v"(af[5].u), "=v"(af[6].u), "=v"(af[7].u),
          "=v"(af[8].u), "=v"(af[9].u), "=v"(af[10].u), "=v"(af[11].u),
          "=v"(af[12].u), "=v"(af[13].u), "=v"(af[14].u), "=v"(af[15].u)
        : "v"(aptr)
        : "memory");

    // w prefetch for this step: issue before the MFMA loop so HBM latency
    // hides under MFMA + reduce (consumed in phase B).
    u16 wra[4], wrz[4];
    if (kh == 0) {
      #pragma unroll
      for (int r = 0; r < 4; ++r) {
        size_t wrow = ((size_t)(b0 + r) * 1000 + t) * 2048;
        wra[r] = w[wrow + ja];
        wrz[r] = w[wrow + jz];
      }
    }

    float4v a0 = (float4v){0, 0, 0, 0}, a1 = (float4v){0, 0, 0, 0};
    #pragma unroll
    for (int kk = 0; kk < 16; ++kk) {
      a0 = __builtin_amdgcn_mfma_f32_16x16x32_f16(af[kk].h, uf0[kk].h, a0, 0, 0, 0);
      a1 = __builtin_amdgcn_mfma_f32_16x16x32_f16(af[kk].h, uf1[kk].h, a1, 0, 0, 0);
    }
    if (kh == 1) { red[mh][0][lane] = a0; red[mh][1][lane] = a1; }
    __syncthreads();  // the only block barrier per step (LDS red hazard)

    if (kh == 0) {
      a0 += red[mh][0][lane];
      a1 += red[mh][1][lane];
      const int p = t & 1;
      // ---- R1 publish: per-batch partial stats, epoch-tagged, fire-and-forget ----
      #pragma unroll
      for (int r = 0; r < 4; ++r) {
        float sv = a0[r] + a1[r];
        float qv = a0[r] * a0[r] + a1[r] * a1[r];
        #pragma unroll
        for (int off = 1; off < 16; off <<= 1) {
          sv += __shfl_xor(sv, off, 64);
          qv += __shfl_xor(qv, off, 64);
        }
        if (col == 0) {
          float* dst = pstats + (((size_t)p * 32 + (b0 + r)) * 64 + beta) * 4;
          store_coh_tag2(dst, sv, tag);       // [s | tag]
          store_coh_tag2(dst + 2, qv, tag);   // [q | tag]
        }
      }
      // ---- R1 poll-gather: re-issue loads until all 64 blocks' tags match ----
      // lane (col,quad) covers batches b0..b0+3 x blocks col*4..col*4+3
      float4v c[16];
      const float* rb = pstats + ((size_t)p * 32 + b0) * 256 + col * 16;
      int ok;
      do {
        asm volatile(
            "global_load_dwordx4 %0,  %16, off sc0 sc1\n\t"
            "global_load_dwordx4 %1,  %16, off offset:16   sc0 sc1\n\t"
            "global_load_dwordx4 %2,  %16, off offset:32   sc0 sc1\n\t"
            "global_load_dwordx4 %3,  %16, off offset:48   sc0 sc1\n\t"
            "global_load_dwordx4 %4,  %16, off offset:1024 sc0 sc1\n\t"
            "global_load_dwordx4 %5,  %16, off offset:1040 sc0 sc1\n\t"
            "global_load_dwordx4 %6,  %16, off offset:1056 sc0 sc1\n\t"
            "global_load_dwordx4 %7,  %16, off offset:1072 sc0 sc1\n\t"
            "global_load_dwordx4 %8,  %16, off offset:2048 sc0 sc1\n\t"
            "global_load_dwordx4 %9,  %16, off offset:2064 sc0 sc1\n\t"
            "global_load_dwordx4 %10, %16, off offset:2080 sc0 sc1\n\t"
            "global_load_dwordx4 %11, %16, off offset:2096 sc0 sc1\n\t"
            "global_load_dwordx4 %12, %16, off offset:3072 sc0 sc1\n\t"
            "global_load_dwordx4 %13, %16, off offset:3088 sc0 sc1\n\t"
            "global_load_dwordx4 %14, %16, off offset:3104 sc0 sc1\n\t"
            "global_load_dwordx4 %15, %16, off offset:3120 sc0 sc1\n\t"
            "s_waitcnt vmcnt(0)"
            : "=v"(c[0]), "=v"(c[1]), "=v"(c[2]), "=v"(c[3]),
              "=v"(c[4]), "=v"(c[5]), "=v"(c[6]), "=v"(c[7]),
              "=v"(c[8]), "=v"(c[9]), "=v"(c[10]), "=v"(c[11]),
              "=v"(c[12]), "=v"(c[13]), "=v"(c[14]), "=v"(c[15])
            : "v"(rb)
            : "memory");
        int okl = 1;
        #pragma unroll
        for (int i = 0; i < 16; ++i)
          okl &= (__float_as_uint(c[i][1]) == tag && __float_as_uint(c[i][3]) == tag) ? 1 : 0;
        ok = __all(okl);
      } while (!ok);

      // ---- phase B: LN + gates + h update ----
      #pragma unroll
      for (int r = 0; r < 4; ++r) {
        float sm = c[4 * r][0] + c[4 * r + 1][0] + c[4 * r + 2][0] + c[4 * r + 3][0];
        float sq = c[4 * r][2] + c[4 * r + 1][2] + c[4 * r + 2][2] + c[4 * r + 3][2];
        #pragma unroll
        for (int off = 1; off < 16; off <<= 1) {
          sm += __shfl_xor(sm, off, 64);
          sq += __shfl_xor(sq, off, 64);
        }
        float mean = sm * (1.f / 2048.f);
        float var = sq * (1.f / 2048.f) - mean * mean;
        float inv = rsqrtf(var + 1e-5f);
        float ga = h2f(wra[r]) * ssa.x + ssa.y + (a0[r] - mean) * inv;
        float gz = h2f(wrz[r]) * ssz.x + ssz.y + (a1[r] - mean) * inv;
        float z = 1.f / (1.f + __expf(-gz));
        float rl = ga > 0.f ? ga : 0.f;
        float h = z * hreg[r] + (1.f - z) * rl;
        hreg[r] = h;
        store_coh_u16(hbuf + (b0 + r) * 1024 + ja, f2h(h));
      }
      // ---- R2 publish: drain h stores, then this wave's epoch flag ----
      asm volatile("s_waitcnt vmcnt(0)" ::: "memory");
      if (lane == 0) store_coh_u32(flags + beta * 16 + mh, tag);
      // output stores off the critical path (drain under the poll below)
      #pragma unroll
      for (int r = 0; r < 4; ++r) {
        size_t orow = ((size_t)(b0 + r) * 1000 + t) * 1024 + ja;
        if (OUT_F32) out32[orow] = hreg[r]; else out16[orow] = f2h(hreg[r]);
      }
    }
    // ---- R2 poll: all 4 waves wait for both writer waves of all 64 blocks ----
    {
      uint2v v;
      do {
        asm volatile("global_load_dwordx2 %0, %1, off sc0 sc1\n\ts_waitcnt vmcnt(0)"
                     : "=v"(v) : "v"(flags + (size_t)lane * 16) : "memory");
      } while (!__all((int)(v[0] >= tag && v[1] >= tag)));
    }
  }
}

extern "C" void kernel_launch(void* const* d_in, const int* in_sizes, int n_in,
                              void* d_out, int out_size, void* d_ws, size_t ws_size,
                              hipStream_t stream) {
  (void)in_sizes; (void)n_in; (void)out_size;
  const float* x  = (const float*)d_in[0];
  const float* W1 = (const float*)d_in[1];
  const float* U1 = (const float*)d_in[2];
  const float* g1 = (const float*)d_in[3];
  const float* b1 = (const float*)d_in[4];
  const float* W2 = (const float*)d_in[5];
  const float* U2 = (const float*)d_in[6];
  const float* g2 = (const float*)d_in[7];
  const float* b2 = (const float*)d_in[8];

  char* ws = (char*)d_ws;
  size_t o = 0;
  auto take = [&](size_t bytes) { size_t r = o; o = (o + bytes + 255) & ~(size_t)255; return r; };
  u16* wbuf  = (u16*)(ws + take(32000ULL * 2048 * 2));   // 131 MB, reused by both layers
  u16* h1seq = (u16*)(ws + take(32000ULL * 1024 * 2));   // 65 MB layer-1 output (fp16)
  u16* xb    = (u16*)(ws + take(32000ULL * 80 * 2));
  u16* W1b   = (u16*)(ws + take(2048ULL * 80 * 2));
  u16* W2b   = (u16*)(ws + take(2048ULL * 1024 * 2));
  u16* U1b   = (u16*)(ws + take(2048ULL * 1024 * 2));
  u16* U2b   = (u16*)(ws + take(2048ULL * 1024 * 2));
  float2* ss1 = (float2*)(ws + take(2048 * 8));
  float2* ss2 = (float2*)(ws + take(2048 * 8));
  size_t zbase = o;  // everything below must start zeroed
  float* acc1 = (float*)(ws + take(2048 * 8));
  float* acc2 = (float*)(ws + take(2048 * 8));
  float* pstats1 = (float*)(ws + take(2ULL * 32 * 64 * 4 * 4));
  float* pstats2 = (float*)(ws + take(2ULL * 32 * 64 * 4 * 4));
  unsigned* flags1 = (unsigned*)(ws + take(64 * 64));
  unsigned* flags2 = (unsigned*)(ws + take(64 * 64));
  u16* hbuf1 = (u16*)(ws + take(32 * 1024 * 2));
  u16* hbuf2 = (u16*)(ws + take(32 * 1024 * 2));
  size_t zlen = o - zbase;
  if (ws_size < o) return;

  (void)hipMemsetAsync(ws + zbase, 0, zlen, stream);

  cvt_f32_f16<<<1280, 256, 0, stream>>>(x, xb, 32000 * 80);
  cvt_f32_f16<<<160, 256, 0, stream>>>(W1, W1b, 2048 * 80);
  cvt_f32_f16<<<1024, 256, 0, stream>>>(U1, U1b, 2048 * 1024);
  cvt_f32_f16<<<1024, 256, 0, stream>>>(W2, W2b, 2048 * 1024);
  cvt_f32_f16<<<1024, 256, 0, stream>>>(U2, U2b, 2048 * 1024);

  // ---- layer 1 ----
  gemm_f16<<<dim3(16, 250), 256, 0, stream>>>(xb, W1b, wbuf, 80);
  bn_stats<<<dim3(8, 125), 256, 0, stream>>>(wbuf, acc1);
  bn_final<<<8, 256, 0, stream>>>(acc1, g1, b1, ss1);
  rec_kernel<0><<<64, 256, 0, stream>>>(wbuf, ss1, U1b, hbuf1, pstats1, flags1, h1seq, nullptr);

  // ---- layer 2 ----
  gemm_f16<<<dim3(16, 250), 256, 0, stream>>>(h1seq, W2b, wbuf, 1024);
  bn_stats<<<dim3(8, 125), 256, 0, stream>>>(wbuf, acc2);
  bn_final<<<8, 256, 0, stream>>>(acc2, g2, b2, ss2);
  rec_kernel<1><<<64, 256, 0, stream>>>(wbuf, ss2, U2b, hbuf2, pstats2, flags2, nullptr, (float*)d_out);
}

// Round 3
// 13728.773 us; speedup vs baseline: 1.4466x; 1.4466x over previous
//
#include <hip/hip_runtime.h>

typedef unsigned short u16;
typedef _Float16 f16;
typedef f16 half8 __attribute__((ext_vector_type(8)));
typedef float float4v __attribute__((ext_vector_type(4)));

union HV { uint4 u; half8 h; u16 s[8]; };

__device__ __forceinline__ float h2f(u16 u) { union { u16 u; f16 h; } c; c.u = u; return (float)c.h; }
__device__ __forceinline__ u16 f2h(float f) { union { u16 u; f16 h; } c; c.h = (f16)f; return c.u; }

// ---- coherent (cross-XCD) access helpers: sc0 sc1 => operate at LLC, bypass XCD L2 ----
__device__ __forceinline__ void store_coh_u16(u16* p, unsigned v) {
  asm volatile("global_store_short %0, %1, off sc0 sc1" :: "v"(p), "v"(v) : "memory");
}
__device__ __forceinline__ void store_coh_u32(void* p, unsigned v) {
  asm volatile("global_store_dword %0, %1, off sc0 sc1" :: "v"(p), "v"(v) : "memory");
}
// single-instruction 8B store of two f32 (atomically visible)
__device__ __forceinline__ void store_coh_f32x2(float* p, float a, float b) {
  unsigned long long pk = (unsigned long long)__float_as_uint(a) |
                          ((unsigned long long)__float_as_uint(b) << 32);
  asm volatile("global_store_dwordx2 %0, %1, off sc0 sc1" :: "v"(p), "v"(pk) : "memory");
}

// ---------------- fp32 -> fp16 convert ----------------
__global__ void cvt_f32_f16(const float* __restrict__ s, u16* __restrict__ d, int n) {
  for (int i = blockIdx.x * blockDim.x + threadIdx.x; i < n; i += gridDim.x * blockDim.x)
    d[i] = f2h(s[i]);
}

// ---------------- GEMM: C[M][2048] = A[M][K] * B[2048][K]^T (fp16 in/out, fp32 accum) ----------
__global__ __launch_bounds__(256) void gemm_f16(const u16* __restrict__ A, const u16* __restrict__ B,
                                                u16* __restrict__ C, int K) {
  __shared__ u16 As[128][40];
  __shared__ u16 Bs[128][40];
  const int tid = threadIdx.x, lane = tid & 63, wid = tid >> 6;
  const int col = lane & 15, quad = lane >> 4;
  const int wm = (wid & 1) * 64, wn = (wid >> 1) * 64;
  const int n0 = blockIdx.x * 128;
  const int m0 = blockIdx.y * 128;
  float4v acc[4][4];
  #pragma unroll
  for (int i = 0; i < 4; ++i)
    #pragma unroll
    for (int j = 0; j < 4; ++j) acc[i][j] = (float4v){0.f, 0.f, 0.f, 0.f};

  const int srow = tid >> 2;
  const int schunk = (tid & 3) * 8;

  for (int k0 = 0; k0 < K; k0 += 32) {
    __syncthreads();
    #pragma unroll
    for (int r2 = 0; r2 < 2; ++r2) {
      int row = srow + 64 * r2;
      int kk = k0 + schunk;
      uint4 av = {0, 0, 0, 0}, bv = {0, 0, 0, 0};
      if (kk + 8 <= K) {
        av = *(const uint4*)(A + (size_t)(m0 + row) * K + kk);
        bv = *(const uint4*)(B + (size_t)(n0 + row) * K + kk);
      }
      *(uint4*)&As[row][schunk] = av;
      *(uint4*)&Bs[row][schunk] = bv;
    }
    __syncthreads();
    HV af[4], bf[4];
    #pragma unroll
    for (int i = 0; i < 4; ++i) af[i].u = *(const uint4*)&As[wm + i * 16 + col][quad * 8];
    #pragma unroll
    for (int j = 0; j < 4; ++j) bf[j].u = *(const uint4*)&Bs[wn + j * 16 + col][quad * 8];
    #pragma unroll
    for (int i = 0; i < 4; ++i)
      #pragma unroll
      for (int j = 0; j < 4; ++j)
        acc[i][j] = __builtin_amdgcn_mfma_f32_16x16x32_f16(af[i].h, bf[j].h, acc[i][j], 0, 0, 0);
  }
  #pragma unroll
  for (int i = 0; i < 4; ++i)
    #pragma unroll
    for (int j = 0; j < 4; ++j)
      #pragma unroll
      for (int r = 0; r < 4; ++r) {
        int m = m0 + wm + i * 16 + quad * 4 + r;
        int n = n0 + wn + j * 16 + col;
        C[(size_t)m * 2048 + n] = f2h(acc[i][j][r]);
      }
}

// ---------------- BatchNorm stats over 32000 rows ----------------
__global__ void bn_stats(const u16* __restrict__ C, float* __restrict__ acc) {
  int c = blockIdx.x * 256 + threadIdx.x;
  int r0 = blockIdx.y * 256;
  float s = 0.f, q = 0.f;
  for (int r = r0; r < r0 + 256; ++r) {
    float v = h2f(C[(size_t)r * 2048 + c]);
    s += v; q += v * v;
  }
  atomicAdd(&acc[2 * c], s);
  atomicAdd(&acc[2 * c + 1], q);
}

__global__ void bn_final(const float* __restrict__ acc, const float* __restrict__ g,
                         const float* __restrict__ b, float2* __restrict__ ss) {
  int c = blockIdx.x * 256 + threadIdx.x;
  float mean = acc[2 * c] * (1.f / 32000.f);
  float var = acc[2 * c + 1] * (1.f / 32000.f) - mean * mean;
  float sc = g[c] * rsqrtf(var + 1e-5f);
  float2 o; o.x = sc; o.y = b[c] - mean * sc;
  ss[c] = o;
}

// ---------------- persistent recurrence ----------------
// Batches are INDEPENDENT (LN is per batch-row): 2 independent sync domains of
// 32 blocks; domain d owns batches [16d,16d+16). Block beta owns 64 gate cols
// (32 h-cols): a-cols [32b,32b+32), z-cols 1024+[32b,32b+32). Wave kh (0..3)
// holds U for K-slice [256kh,256kh+256) in VGPRs.
//
// Per step (wave 0 = compute wave; waves 1-3 only MFMA + LDS reduce):
//   phase A: all waves load full h (coherent), 32 MFMAs; kh>0 write partials
//            to LDS; __syncthreads (the only block barrier per step).
//   wave 0:  K-reduce from LDS; per-batch (s,q) over its 64 cols; 4x dwordx2
//            coherent store; vmcnt(0); B1 flag; w(t+1) prefetch into wn* regs
//            (NOT the live wa* regs — that was the r2 correctness bug) so its
//            HBM latency hides under the B1 poll; poll 32 B1 flags;
//            gather 32 blocks' (s,q) once (4x dwordx4); LN+gates (uses wa*);
//            wa* <- wn*; h stores; vmcnt(0); B2 flag; out stores (drain under
//            poll); poll 32 B2 flags; release waves 1-3 via LDS epoch (rel2).
// Polling is flag-only, 1 wave/block -> no LLC data-poll contention (the r1
// regression). Safety: all 4 waves' h loads drain before S1, so B1 flag(t)
// implies block's h reads done -> h stores(t) can't race; pstats slot (t&1)
// reuse is 2 epochs behind any reader; flags/rel2 are monotonic u32 epochs;
// LDS red protected by S1 (write->read) and rel2 (read->next write).
//
// pstats: [dom][phase][batch16][block32][s,q] f32 ; flags: [bar][dom][32][16] u32
template <int OUT_F32>
__global__ __launch_bounds__(256, 1) void rec_kernel(
    const u16* __restrict__ w,      // [32*1000][2048] fp16 (pre-BN)
    const float2* __restrict__ ss,  // [2048] BN scale/shift
    const u16* __restrict__ U,      // [2048][1024] fp16
    u16* hbuf,                      // [32][1024] fp16 (current h)
    float* pstats,                  // [2][2][16][32][2] f32
    unsigned* flags,                // [2][2][32][16] u32
    u16* out16, float* out32) {
  const int tid = threadIdx.x, lane = tid & 63, kh = tid >> 6;
  const int d = blockIdx.x >> 5, beta = blockIdx.x & 31;
  const int col = lane & 15, quad = lane >> 4;
  __shared__ float4v red[3][4][64];
  __shared__ unsigned rel2;
  if (tid == 0) rel2 = 0u;
  __syncthreads();

  const int ja = beta * 32 + col;     // h-col / a-col group 0 (group 1 = +16)

  HV ufA0[8], ufA1[8], ufZ0[8], ufZ1[8];   // U fragments: 64 gate cols x K=256
  #pragma unroll
  for (int kk = 0; kk < 8; ++kk) {
    int k = kh * 256 + kk * 32 + quad * 8;
    ufA0[kk].u = *(const uint4*)(U + (size_t)ja * 1024 + k);
    ufA1[kk].u = *(const uint4*)(U + (size_t)(ja + 16) * 1024 + k);
    ufZ0[kk].u = *(const uint4*)(U + (size_t)(1024 + ja) * 1024 + k);
    ufZ1[kk].u = *(const uint4*)(U + (size_t)(1024 + ja + 16) * 1024 + k);
  }
  float2 ssA0 = ss[ja], ssA1 = ss[ja + 16];
  float2 ssZ0 = ss[1024 + ja], ssZ1 = ss[1024 + ja + 16];

  u16* hb = hbuf + (size_t)d * 16 * 1024;          // this domain's 16 h rows
  float* ps = pstats + (size_t)d * 2048;           // 2*16*32*2 floats
  unsigned* f1 = flags + (size_t)d * 512;          // 32 x 16 u32 (64B stride)
  unsigned* f2 = flags + 1024 + (size_t)d * 512;

  const u16* aptr = hb + (size_t)col * 1024 + kh * 256 + quad * 8;
  const int bloc = quad * 4;                       // local batch base (phase B)

  float hreg[4][2] = {{0.f, 0.f}, {0.f, 0.f}, {0.f, 0.f}, {0.f, 0.f}};
  u16 wa0[4], wa1[4], wz0[4], wz1[4];              // w for CURRENT step
  if (kh == 0) {
    #pragma unroll
    for (int r = 0; r < 4; ++r) {
      const u16* wr = w + ((size_t)(d * 16 + bloc + r) * 1000 + 0) * 2048 + ja;
      wa0[r] = wr[0]; wa1[r] = wr[16]; wz0[r] = wr[1024]; wz1[r] = wr[1040];
    }
  }

  for (int t = 0; t < 1000; ++t) {
    const unsigned tag = (unsigned)t + 1u;
    // ---- phase A: coherent h load (8 x 16B) + partial-K MFMA ----
    HV af[8];
    asm volatile(
        "global_load_dwordx4 %0, %8, off sc0 sc1\n\t"
        "global_load_dwordx4 %1, %8, off offset:64  sc0 sc1\n\t"
        "global_load_dwordx4 %2, %8, off offset:128 sc0 sc1\n\t"
        "global_load_dwordx4 %3, %8, off offset:192 sc0 sc1\n\t"
        "global_load_dwordx4 %4, %8, off offset:256 sc0 sc1\n\t"
        "global_load_dwordx4 %5, %8, off offset:320 sc0 sc1\n\t"
        "global_load_dwordx4 %6, %8, off offset:384 sc0 sc1\n\t"
        "global_load_dwordx4 %7, %8, off offset:448 sc0 sc1\n\t"
        "s_waitcnt vmcnt(0)"
        : "=v"(af[0].u), "=v"(af[1].u), "=v"(af[2].u), "=v"(af[3].u),
          "=v"(af[4].u), "=v"(af[5].u), "=v"(af[6].u), "=v"(af[7].u)
        : "v"(aptr)
        : "memory");

    float4v aA0 = (float4v){0.f, 0.f, 0.f, 0.f};
    float4v aA1 = (float4v){0.f, 0.f, 0.f, 0.f};
    float4v aZ0 = (float4v){0.f, 0.f, 0.f, 0.f};
    float4v aZ1 = (float4v){0.f, 0.f, 0.f, 0.f};
    #pragma unroll
    for (int kk = 0; kk < 8; ++kk) {
      aA0 = __builtin_amdgcn_mfma_f32_16x16x32_f16(af[kk].h, ufA0[kk].h, aA0, 0, 0, 0);
      aA1 = __builtin_amdgcn_mfma_f32_16x16x32_f16(af[kk].h, ufA1[kk].h, aA1, 0, 0, 0);
      aZ0 = __builtin_amdgcn_mfma_f32_16x16x32_f16(af[kk].h, ufZ0[kk].h, aZ0, 0, 0, 0);
      aZ1 = __builtin_amdgcn_mfma_f32_16x16x32_f16(af[kk].h, ufZ1[kk].h, aZ1, 0, 0, 0);
    }
    if (kh) {
      red[kh - 1][0][lane] = aA0; red[kh - 1][1][lane] = aA1;
      red[kh - 1][2][lane] = aZ0; red[kh - 1][3][lane] = aZ1;
    }
    __syncthreads();   // S1: LDS partials ready

    if (kh == 0) {
      aA0 += red[0][0][lane] + red[1][0][lane] + red[2][0][lane];
      aA1 += red[0][1][lane] + red[1][1][lane] + red[2][1][lane];
      aZ0 += red[0][2][lane] + red[1][2][lane] + red[2][2][lane];
      aZ1 += red[0][3][lane] + red[1][3][lane] + red[2][3][lane];
      const int p = t & 1;
      // ---- per-batch partial stats over this block's 64 gate cols ----
      #pragma unroll
      for (int r = 0; r < 4; ++r) {
        float sv = aA0[r] + aA1[r] + aZ0[r] + aZ1[r];
        float qv = aA0[r] * aA0[r] + aA1[r] * aA1[r] + aZ0[r] * aZ0[r] + aZ1[r] * aZ1[r];
        #pragma unroll
        for (int off = 1; off < 16; off <<= 1) {
          sv += __shfl_xor(sv, off, 64);
          qv += __shfl_xor(qv, off, 64);
        }
        if (col == 0)
          store_coh_f32x2(ps + (((size_t)p * 16 + bloc + r) * 32 + beta) * 2, sv, qv);
      }
      asm volatile("s_waitcnt vmcnt(0)" ::: "memory");   // stats ack only
      if (lane == 0) store_coh_u32(f1 + (size_t)beta * 16, tag);
      // w(t+1) prefetch into SEPARATE regs: latency hides under the B1 poll
      u16 wn_a0[4], wn_a1[4], wn_z0[4], wn_z1[4];
      {
        int tn = t < 999 ? t + 1 : t;
        #pragma unroll
        for (int r = 0; r < 4; ++r) {
          const u16* wr = w + ((size_t)(d * 16 + bloc + r) * 1000 + tn) * 2048 + ja;
          wn_a0[r] = wr[0]; wn_a1[r] = wr[16]; wn_z0[r] = wr[1024]; wn_z1[r] = wr[1040];
        }
      }
      // ---- B1 poll: 32 flags, lanes<32, flag-only traffic ----
      {
        unsigned fv = tag; int ok;
        do {
          if (lane < 32)
            asm volatile("global_load_dword %0, %1, off sc0 sc1\n\ts_waitcnt vmcnt(0)"
                         : "=v"(fv) : "v"(f1 + (size_t)lane * 16) : "memory");
          ok = __all(lane < 32 ? (int)(fv >= tag) : 1);
        } while (!ok);
      }
      // ---- gather all 32 blocks' (s,q) once ----
      float4v cc[4];
      const float* rb = ps + ((size_t)p * 16 + bloc) * 64 + col * 4;
      asm volatile(
          "global_load_dwordx4 %0, %4, off sc0 sc1\n\t"
          "global_load_dwordx4 %1, %4, off offset:256 sc0 sc1\n\t"
          "global_load_dwordx4 %2, %4, off offset:512 sc0 sc1\n\t"
          "global_load_dwordx4 %3, %4, off offset:768 sc0 sc1\n\t"
          "s_waitcnt vmcnt(0)"
          : "=v"(cc[0]), "=v"(cc[1]), "=v"(cc[2]), "=v"(cc[3])
          : "v"(rb)
          : "memory");
      // ---- LN + gates + h update (consumes wa* = w(t)) ----
      #pragma unroll
      for (int r = 0; r < 4; ++r) {
        float sm = cc[r][0] + cc[r][2];
        float sq = cc[r][1] + cc[r][3];
        #pragma unroll
        for (int off = 1; off < 16; off <<= 1) {
          sm += __shfl_xor(sm, off, 64);
          sq += __shfl_xor(sq, off, 64);
        }
        float mean = sm * (1.f / 2048.f);
        float var = sq * (1.f / 2048.f) - mean * mean;
        float inv = rsqrtf(var + 1e-5f);
        float ga0 = h2f(wa0[r]) * ssA0.x + ssA0.y + (aA0[r] - mean) * inv;
        float ga1 = h2f(wa1[r]) * ssA1.x + ssA1.y + (aA1[r] - mean) * inv;
        float gz0 = h2f(wz0[r]) * ssZ0.x + ssZ0.y + (aZ0[r] - mean) * inv;
        float gz1 = h2f(wz1[r]) * ssZ1.x + ssZ1.y + (aZ1[r] - mean) * inv;
        float z0 = 1.f / (1.f + __expf(-gz0));
        float z1 = 1.f / (1.f + __expf(-gz1));
        float h0 = z0 * hreg[r][0] + (1.f - z0) * (ga0 > 0.f ? ga0 : 0.f);
        float h1 = z1 * hreg[r][1] + (1.f - z1) * (ga1 > 0.f ? ga1 : 0.f);
        hreg[r][0] = h0; hreg[r][1] = h1;
        u16* hp = hb + (size_t)(bloc + r) * 1024 + ja;
        store_coh_u16(hp, (unsigned)f2h(h0));
        store_coh_u16(hp + 16, (unsigned)f2h(h1));
      }
      // rotate w regs: wa* <- wn* (w(t+1) for next iteration)
      #pragma unroll
      for (int r = 0; r < 4; ++r) {
        wa0[r] = wn_a0[r]; wa1[r] = wn_a1[r];
        wz0[r] = wn_z0[r]; wz1[r] = wn_z1[r];
      }
      asm volatile("s_waitcnt vmcnt(0)" ::: "memory");   // h ack
      if (lane == 0) store_coh_u32(f2 + (size_t)beta * 16, tag);
      // output stores: off the critical path (drain under the B2 poll)
      #pragma unroll
      for (int r = 0; r < 4; ++r) {
        size_t orow = ((size_t)(d * 16 + bloc + r) * 1000 + t) * 1024 + ja;
        if (OUT_F32) { out32[orow] = hreg[r][0]; out32[orow + 16] = hreg[r][1]; }
        else         { out16[orow] = f2h(hreg[r][0]); out16[orow + 16] = f2h(hreg[r][1]); }
      }
      // ---- B2 poll + LDS release ----
      {
        unsigned fv = tag; int ok;
        do {
          if (lane < 32)
            asm volatile("global_load_dword %0, %1, off sc0 sc1\n\ts_waitcnt vmcnt(0)"
                         : "=v"(fv) : "v"(f2 + (size_t)lane * 16) : "memory");
          ok = __all(lane < 32 ? (int)(fv >= tag) : 1);
        } while (!ok);
      }
      if (tid == 0) *(volatile unsigned*)&rel2 = tag;
    } else {
      while (*(volatile unsigned*)&rel2 < tag) {}
    }
  }
}

extern "C" void kernel_launch(void* const* d_in, const int* in_sizes, int n_in,
                              void* d_out, int out_size, void* d_ws, size_t ws_size,
                              hipStream_t stream) {
  (void)in_sizes; (void)n_in; (void)out_size;
  const float* x  = (const float*)d_in[0];
  const float* W1 = (const float*)d_in[1];
  const float* U1 = (const float*)d_in[2];
  const float* g1 = (const float*)d_in[3];
  const float* b1 = (const float*)d_in[4];
  const float* W2 = (const float*)d_in[5];
  const float* U2 = (const float*)d_in[6];
  const float* g2 = (const float*)d_in[7];
  const float* b2 = (const float*)d_in[8];

  char* ws = (char*)d_ws;
  size_t o = 0;
  auto take = [&](size_t bytes) { size_t r = o; o = (o + bytes + 255) & ~(size_t)255; return r; };
  u16* wbuf  = (u16*)(ws + take(32000ULL * 2048 * 2));   // 131 MB, reused by both layers
  u16* h1seq = (u16*)(ws + take(32000ULL * 1024 * 2));   // 65 MB layer-1 output (fp16)
  u16* xb    = (u16*)(ws + take(32000ULL * 80 * 2));
  u16* W1b   = (u16*)(ws + take(2048ULL * 80 * 2));
  u16* W2b   = (u16*)(ws + take(2048ULL * 1024 * 2));
  u16* U1b   = (u16*)(ws + take(2048ULL * 1024 * 2));
  u16* U2b   = (u16*)(ws + take(2048ULL * 1024 * 2));
  float2* ss1 = (float2*)(ws + take(2048 * 8));
  float2* ss2 = (float2*)(ws + take(2048 * 8));
  size_t zbase = o;  // everything below must start zeroed
  float* acc1 = (float*)(ws + take(2048 * 8));
  float* acc2 = (float*)(ws + take(2048 * 8));
  float* pstats1 = (float*)(ws + take(2ULL * 2 * 16 * 32 * 2 * 4));   // 16 KB
  float* pstats2 = (float*)(ws + take(2ULL * 2 * 16 * 32 * 2 * 4));
  unsigned* flags1 = (unsigned*)(ws + take(2ULL * 2 * 32 * 16 * 4));  // 8 KB
  unsigned* flags2 = (unsigned*)(ws + take(2ULL * 2 * 32 * 16 * 4));
  u16* hbuf1 = (u16*)(ws + take(32 * 1024 * 2));
  u16* hbuf2 = (u16*)(ws + take(32 * 1024 * 2));
  size_t zlen = o - zbase;
  if (ws_size < o) return;

  (void)hipMemsetAsync(ws + zbase, 0, zlen, stream);

  cvt_f32_f16<<<1280, 256, 0, stream>>>(x, xb, 32000 * 80);
  cvt_f32_f16<<<160, 256, 0, stream>>>(W1, W1b, 2048 * 80);
  cvt_f32_f16<<<1024, 256, 0, stream>>>(U1, U1b, 2048 * 1024);
  cvt_f32_f16<<<1024, 256, 0, stream>>>(W2, W2b, 2048 * 1024);
  cvt_f32_f16<<<1024, 256, 0, stream>>>(U2, U2b, 2048 * 1024);

  // ---- layer 1 ----
  gemm_f16<<<dim3(16, 250), 256, 0, stream>>>(xb, W1b, wbuf, 80);
  bn_stats<<<dim3(8, 125), 256, 0, stream>>>(wbuf, acc1);
  bn_final<<<8, 256, 0, stream>>>(acc1, g1, b1, ss1);
  rec_kernel<0><<<64, 256, 0, stream>>>(wbuf, ss1, U1b, hbuf1, pstats1, flags1, h1seq, nullptr);

  // ---- layer 2 ----
  gemm_f16<<<dim3(16, 250), 256, 0, stream>>>(h1seq, W2b, wbuf, 1024);
  bn_stats<<<dim3(8, 125), 256, 0, stream>>>(wbuf, acc2);
  bn_final<<<8, 256, 0, stream>>>(acc2, g2, b2, ss2);
  rec_kernel<1><<<64, 256, 0, stream>>>(wbuf, ss2, U2b, hbuf2, pstats2, flags2, nullptr, (float*)d_out);
}

// Round 4
// 12950.606 us; speedup vs baseline: 1.5335x; 1.0601x over previous
//
#include <hip/hip_runtime.h>

typedef unsigned short u16;
typedef _Float16 f16;
typedef f16 half8 __attribute__((ext_vector_type(8)));
typedef float float4v __attribute__((ext_vector_type(4)));

union HV { uint4 u; half8 h; u16 s[8]; };

__device__ __forceinline__ float h2f(u16 u) { union { u16 u; f16 h; } c; c.u = u; return (float)c.h; }
__device__ __forceinline__ u16 f2h(float f) { union { u16 u; f16 h; } c; c.h = (f16)f; return c.u; }

// ---- coherent (cross-XCD) access helpers: sc0 sc1 => operate at LLC, bypass XCD L2 ----
__device__ __forceinline__ void store_coh_u16(u16* p, unsigned v) {
  asm volatile("global_store_short %0, %1, off sc0 sc1" :: "v"(p), "v"(v) : "memory");
}
__device__ __forceinline__ void store_coh_u32(void* p, unsigned v) {
  asm volatile("global_store_dword %0, %1, off sc0 sc1" :: "v"(p), "v"(v) : "memory");
}
// single-instruction 8B store: [f32 payload | u32 epoch tag] — atomically visible
__device__ __forceinline__ void store_coh_f32_tag(float* p, float val, unsigned tag) {
  unsigned long long pk = (unsigned long long)__float_as_uint(val) |
                          ((unsigned long long)tag << 32);
  asm volatile("global_store_dwordx2 %0, %1, off sc0 sc1" :: "v"(p), "v"(pk) : "memory");
}

// ---------------- fp32 -> fp16 convert ----------------
__global__ void cvt_f32_f16(const float* __restrict__ s, u16* __restrict__ d, int n) {
  for (int i = blockIdx.x * blockDim.x + threadIdx.x; i < n; i += gridDim.x * blockDim.x)
    d[i] = f2h(s[i]);
}

// ---------------- GEMM: C[M][2048] = A[M][K] * B[2048][K]^T (fp16 in/out, fp32 accum) ----------
__global__ __launch_bounds__(256) void gemm_f16(const u16* __restrict__ A, const u16* __restrict__ B,
                                                u16* __restrict__ C, int K) {
  __shared__ u16 As[128][40];
  __shared__ u16 Bs[128][40];
  const int tid = threadIdx.x, lane = tid & 63, wid = tid >> 6;
  const int col = lane & 15, quad = lane >> 4;
  const int wm = (wid & 1) * 64, wn = (wid >> 1) * 64;
  const int n0 = blockIdx.x * 128;
  const int m0 = blockIdx.y * 128;
  float4v acc[4][4];
  #pragma unroll
  for (int i = 0; i < 4; ++i)
    #pragma unroll
    for (int j = 0; j < 4; ++j) acc[i][j] = (float4v){0.f, 0.f, 0.f, 0.f};

  const int srow = tid >> 2;
  const int schunk = (tid & 3) * 8;

  for (int k0 = 0; k0 < K; k0 += 32) {
    __syncthreads();
    #pragma unroll
    for (int r2 = 0; r2 < 2; ++r2) {
      int row = srow + 64 * r2;
      int kk = k0 + schunk;
      uint4 av = {0, 0, 0, 0}, bv = {0, 0, 0, 0};
      if (kk + 8 <= K) {
        av = *(const uint4*)(A + (size_t)(m0 + row) * K + kk);
        bv = *(const uint4*)(B + (size_t)(n0 + row) * K + kk);
      }
      *(uint4*)&As[row][schunk] = av;
      *(uint4*)&Bs[row][schunk] = bv;
    }
    __syncthreads();
    HV af[4], bf[4];
    #pragma unroll
    for (int i = 0; i < 4; ++i) af[i].u = *(const uint4*)&As[wm + i * 16 + col][quad * 8];
    #pragma unroll
    for (int j = 0; j < 4; ++j) bf[j].u = *(const uint4*)&Bs[wn + j * 16 + col][quad * 8];
    #pragma unroll
    for (int i = 0; i < 4; ++i)
      #pragma unroll
      for (int j = 0; j < 4; ++j)
        acc[i][j] = __builtin_amdgcn_mfma_f32_16x16x32_f16(af[i].h, bf[j].h, acc[i][j], 0, 0, 0);
  }
  #pragma unroll
  for (int i = 0; i < 4; ++i)
    #pragma unroll
    for (int j = 0; j < 4; ++j)
      #pragma unroll
      for (int r = 0; r < 4; ++r) {
        int m = m0 + wm + i * 16 + quad * 4 + r;
        int n = n0 + wn + j * 16 + col;
        C[(size_t)m * 2048 + n] = f2h(acc[i][j][r]);
      }
}

// ---------------- BatchNorm stats over 32000 rows ----------------
__global__ void bn_stats(const u16* __restrict__ C, float* __restrict__ acc) {
  int c = blockIdx.x * 256 + threadIdx.x;
  int r0 = blockIdx.y * 256;
  float s = 0.f, q = 0.f;
  for (int r = r0; r < r0 + 256; ++r) {
    float v = h2f(C[(size_t)r * 2048 + c]);
    s += v; q += v * v;
  }
  atomicAdd(&acc[2 * c], s);
  atomicAdd(&acc[2 * c + 1], q);
}

__global__ void bn_final(const float* __restrict__ acc, const float* __restrict__ g,
                         const float* __restrict__ b, float2* __restrict__ ss) {
  int c = blockIdx.x * 256 + threadIdx.x;
  float mean = acc[2 * c] * (1.f / 32000.f);
  float var = acc[2 * c + 1] * (1.f / 32000.f) - mean * mean;
  float sc = g[c] * rsqrtf(var + 1e-5f);
  float2 o; o.x = sc; o.y = b[c] - mean * sc;
  ss[c] = o;
}

// ---------------- persistent recurrence ----------------
// 2 independent domains x 32 blocks; domain d owns batches [16d,16d+16).
// Block beta owns 64 gate cols (32 h-cols). Wave kh holds U K-slice in VGPRs.
//
// Per step, TWO communication rounds:
//  R1 (stats): wave 0 stores per-batch LN partials as epoch-tagged 8B halves
//     ([s|tag][q|tag], single dwordx2 each => atomically visible). Readers
//     POLL-GATHER the 16B records directly (8 x dwordx4 per lane, tag-checked)
//     — no store-ack, no flag round. Traffic bounded: 1 wave/block polls,
//     128 B/lane/round, vmcnt-serialized rounds, 8 KB region per domain.
//  R2 (h): h stores -> vmcnt(0) -> per-block epoch flag f2; ALL 4 waves poll
//     the 32 f2 flags (lanes<32, 4B each). No LDS relay (rel2 removed).
//
// Safety: a block's stats(t) is stored after S1, which is after all 4 waves
// drained their h loads => "all 32 stats visible" implies "all h reads of
// step t done" => single-buffer h stores are race-free (gather subsumes B1's
// safety role). pstats parity slot reuse is 2 epochs behind any reader via
// the f2 round. LDS red: write(t) -> S1 -> wave0 read(t) -> f2(t) flag;
// waves 1-3 write red(t+1) only after f2(t) passes. Out stores are plain
// (non-coherent) and sit between flag store and poll (drain under poll).
//
// pstats: [dom][phase][batch16][block32][s,tag,q,tag] f32
// flags:  [dom][32][16] u32 (f2 only)
template <int OUT_F32>
__global__ __launch_bounds__(256, 1) void rec_kernel(
    const u16* __restrict__ w,      // [32*1000][2048] fp16 (pre-BN)
    const float2* __restrict__ ss,  // [2048] BN scale/shift
    const u16* __restrict__ U,      // [2048][1024] fp16
    u16* hbuf,                      // [32][1024] fp16 (current h)
    float* pstats,                  // [2][2][16][32][4] f32
    unsigned* flags,                // [2][32][16] u32
    u16* out16, float* out32) {
  const int tid = threadIdx.x, lane = tid & 63, kh = tid >> 6;
  const int d = blockIdx.x >> 5, beta = blockIdx.x & 31;
  const int col = lane & 15, quad = lane >> 4;
  __shared__ float4v red[3][4][64];

  const int ja = beta * 32 + col;     // h-col / a-col group 0 (group 1 = +16)

  HV ufA0[8], ufA1[8], ufZ0[8], ufZ1[8];   // U fragments: 64 gate cols x K=256
  #pragma unroll
  for (int kk = 0; kk < 8; ++kk) {
    int k = kh * 256 + kk * 32 + quad * 8;
    ufA0[kk].u = *(const uint4*)(U + (size_t)ja * 1024 + k);
    ufA1[kk].u = *(const uint4*)(U + (size_t)(ja + 16) * 1024 + k);
    ufZ0[kk].u = *(const uint4*)(U + (size_t)(1024 + ja) * 1024 + k);
    ufZ1[kk].u = *(const uint4*)(U + (size_t)(1024 + ja + 16) * 1024 + k);
  }
  float2 ssA0 = ss[ja], ssA1 = ss[ja + 16];
  float2 ssZ0 = ss[1024 + ja], ssZ1 = ss[1024 + ja + 16];

  u16* hb = hbuf + (size_t)d * 16 * 1024;          // this domain's 16 h rows
  float* ps = pstats + (size_t)d * 4096;           // 2*16*32*4 floats
  unsigned* f2 = flags + (size_t)d * 512;          // 32 x 16 u32 (64B stride)

  const u16* aptr = hb + (size_t)col * 1024 + kh * 256 + quad * 8;
  const int bloc = quad * 4;                       // local batch base (phase B)

  float hreg[4][2] = {{0.f, 0.f}, {0.f, 0.f}, {0.f, 0.f}, {0.f, 0.f}};
  u16 wa0[4], wa1[4], wz0[4], wz1[4];              // w for CURRENT step
  if (kh == 0) {
    #pragma unroll
    for (int r = 0; r < 4; ++r) {
      const u16* wr = w + ((size_t)(d * 16 + bloc + r) * 1000 + 0) * 2048 + ja;
      wa0[r] = wr[0]; wa1[r] = wr[16]; wz0[r] = wr[1024]; wz1[r] = wr[1040];
    }
  }

  for (int t = 0; t < 1000; ++t) {
    const unsigned tag = (unsigned)t + 1u;
    // ---- phase A: coherent h load (8 x 16B) + partial-K MFMA ----
    HV af[8];
    asm volatile(
        "global_load_dwordx4 %0, %8, off sc0 sc1\n\t"
        "global_load_dwordx4 %1, %8, off offset:64  sc0 sc1\n\t"
        "global_load_dwordx4 %2, %8, off offset:128 sc0 sc1\n\t"
        "global_load_dwordx4 %3, %8, off offset:192 sc0 sc1\n\t"
        "global_load_dwordx4 %4, %8, off offset:256 sc0 sc1\n\t"
        "global_load_dwordx4 %5, %8, off offset:320 sc0 sc1\n\t"
        "global_load_dwordx4 %6, %8, off offset:384 sc0 sc1\n\t"
        "global_load_dwordx4 %7, %8, off offset:448 sc0 sc1\n\t"
        "s_waitcnt vmcnt(0)"
        : "=v"(af[0].u), "=v"(af[1].u), "=v"(af[2].u), "=v"(af[3].u),
          "=v"(af[4].u), "=v"(af[5].u), "=v"(af[6].u), "=v"(af[7].u)
        : "v"(aptr)
        : "memory");

    float4v aA0 = (float4v){0.f, 0.f, 0.f, 0.f};
    float4v aA1 = (float4v){0.f, 0.f, 0.f, 0.f};
    float4v aZ0 = (float4v){0.f, 0.f, 0.f, 0.f};
    float4v aZ1 = (float4v){0.f, 0.f, 0.f, 0.f};
    #pragma unroll
    for (int kk = 0; kk < 8; ++kk) {
      aA0 = __builtin_amdgcn_mfma_f32_16x16x32_f16(af[kk].h, ufA0[kk].h, aA0, 0, 0, 0);
      aA1 = __builtin_amdgcn_mfma_f32_16x16x32_f16(af[kk].h, ufA1[kk].h, aA1, 0, 0, 0);
      aZ0 = __builtin_amdgcn_mfma_f32_16x16x32_f16(af[kk].h, ufZ0[kk].h, aZ0, 0, 0, 0);
      aZ1 = __builtin_amdgcn_mfma_f32_16x16x32_f16(af[kk].h, ufZ1[kk].h, aZ1, 0, 0, 0);
    }
    if (kh) {
      red[kh - 1][0][lane] = aA0; red[kh - 1][1][lane] = aA1;
      red[kh - 1][2][lane] = aZ0; red[kh - 1][3][lane] = aZ1;
    }
    __syncthreads();   // S1: LDS partials ready (after all waves' h loads drained)

    if (kh == 0) {
      aA0 += red[0][0][lane] + red[1][0][lane] + red[2][0][lane];
      aA1 += red[0][1][lane] + red[1][1][lane] + red[2][1][lane];
      aZ0 += red[0][2][lane] + red[1][2][lane] + red[2][2][lane];
      aZ1 += red[0][3][lane] + red[1][3][lane] + red[2][3][lane];
      const int p = t & 1;
      // ---- R1 publish: per-batch tagged partial stats, fire-and-forget ----
      #pragma unroll
      for (int r = 0; r < 4; ++r) {
        float sv = aA0[r] + aA1[r] + aZ0[r] + aZ1[r];
        float qv = aA0[r] * aA0[r] + aA1[r] * aA1[r] + aZ0[r] * aZ0[r] + aZ1[r] * aZ1[r];
        #pragma unroll
        for (int off = 1; off < 16; off <<= 1) {
          sv += __shfl_xor(sv, off, 64);
          qv += __shfl_xor(qv, off, 64);
        }
        if (col == 0) {
          float* dst = ps + (((size_t)p * 16 + bloc + r) * 32 + beta) * 4;
          store_coh_f32_tag(dst, sv, tag);       // [s | tag]
          store_coh_f32_tag(dst + 2, qv, tag);   // [q | tag]
        }
      }
      // w(t+1) prefetch into SEPARATE regs; latency hides under the gather-poll
      u16 wn_a0[4], wn_a1[4], wn_z0[4], wn_z1[4];
      {
        int tn = t < 999 ? t + 1 : t;
        #pragma unroll
        for (int r = 0; r < 4; ++r) {
          const u16* wr = w + ((size_t)(d * 16 + bloc + r) * 1000 + tn) * 2048 + ja;
          wn_a0[r] = wr[0]; wn_a1[r] = wr[16]; wn_z0[r] = wr[1024]; wn_z1[r] = wr[1040];
        }
      }
      // ---- R1 poll-gather: lane (col,quad) covers batches bloc..bloc+3 x
      //      blocks {col, col+16}; re-issue until all 16 tag fields match ----
      float4v g[8];
      const float* rb = ps + ((size_t)p * 16 + bloc) * 128 + col * 4;
      int ok;
      do {
        asm volatile(
            "global_load_dwordx4 %0, %8, off sc0 sc1\n\t"
            "global_load_dwordx4 %1, %8, off offset:256  sc0 sc1\n\t"
            "global_load_dwordx4 %2, %8, off offset:512  sc0 sc1\n\t"
            "global_load_dwordx4 %3, %8, off offset:768  sc0 sc1\n\t"
            "global_load_dwordx4 %4, %8, off offset:1024 sc0 sc1\n\t"
            "global_load_dwordx4 %5, %8, off offset:1280 sc0 sc1\n\t"
            "global_load_dwordx4 %6, %8, off offset:1536 sc0 sc1\n\t"
            "global_load_dwordx4 %7, %8, off offset:1792 sc0 sc1\n\t"
            "s_waitcnt vmcnt(0)"
            : "=v"(g[0]), "=v"(g[1]), "=v"(g[2]), "=v"(g[3]),
              "=v"(g[4]), "=v"(g[5]), "=v"(g[6]), "=v"(g[7])
            : "v"(rb)
            : "memory");
        int okl = 1;
        #pragma unroll
        for (int i = 0; i < 8; ++i)
          okl &= (__float_as_uint(g[i][1]) == tag && __float_as_uint(g[i][3]) == tag) ? 1 : 0;
        ok = __all(okl);
      } while (!ok);

      // ---- LN + gates + h update (consumes wa* = w(t)) ----
      #pragma unroll
      for (int r = 0; r < 4; ++r) {
        float sm = g[2 * r][0] + g[2 * r + 1][0];
        float sq = g[2 * r][2] + g[2 * r + 1][2];
        #pragma unroll
        for (int off = 1; off < 16; off <<= 1) {
          sm += __shfl_xor(sm, off, 64);
          sq += __shfl_xor(sq, off, 64);
        }
        float mean = sm * (1.f / 2048.f);
        float var = sq * (1.f / 2048.f) - mean * mean;
        float inv = rsqrtf(var + 1e-5f);
        float ga0 = h2f(wa0[r]) * ssA0.x + ssA0.y + (aA0[r] - mean) * inv;
        float ga1 = h2f(wa1[r]) * ssA1.x + ssA1.y + (aA1[r] - mean) * inv;
        float gz0 = h2f(wz0[r]) * ssZ0.x + ssZ0.y + (aZ0[r] - mean) * inv;
        float gz1 = h2f(wz1[r]) * ssZ1.x + ssZ1.y + (aZ1[r] - mean) * inv;
        float z0 = 1.f / (1.f + __expf(-gz0));
        float z1 = 1.f / (1.f + __expf(-gz1));
        float h0 = z0 * hreg[r][0] + (1.f - z0) * (ga0 > 0.f ? ga0 : 0.f);
        float h1 = z1 * hreg[r][1] + (1.f - z1) * (ga1 > 0.f ? ga1 : 0.f);
        hreg[r][0] = h0; hreg[r][1] = h1;
        u16* hp = hb + (size_t)(bloc + r) * 1024 + ja;
        store_coh_u16(hp, (unsigned)f2h(h0));
        store_coh_u16(hp + 16, (unsigned)f2h(h1));
      }
      // rotate w regs: wa* <- wn* (w(t+1) for next iteration)
      #pragma unroll
      for (int r = 0; r < 4; ++r) {
        wa0[r] = wn_a0[r]; wa1[r] = wn_a1[r];
        wz0[r] = wn_z0[r]; wz1[r] = wn_z1[r];
      }
      asm volatile("s_waitcnt vmcnt(0)" ::: "memory");   // h ack
      if (lane == 0) store_coh_u32(f2 + (size_t)beta * 16, tag);
      // output stores: plain (non-coherent), drain under the f2 poll
      #pragma unroll
      for (int r = 0; r < 4; ++r) {
        size_t orow = ((size_t)(d * 16 + bloc + r) * 1000 + t) * 1024 + ja;
        if (OUT_F32) { out32[orow] = hreg[r][0]; out32[orow + 16] = hreg[r][1]; }
        else         { out16[orow] = f2h(hreg[r][0]); out16[orow + 16] = f2h(hreg[r][1]); }
      }
    }
    // ---- R2 poll: ALL 4 waves poll the 32 f2 flags directly ----
    {
      unsigned fv = tag; int ok;
      do {
        if (lane < 32)
          asm volatile("global_load_dword %0, %1, off sc0 sc1\n\ts_waitcnt vmcnt(0)"
                       : "=v"(fv) : "v"(f2 + (size_t)lane * 16) : "memory");
        ok = __all(lane < 32 ? (int)(fv >= tag) : 1);
      } while (!ok);
    }
  }
}

extern "C" void kernel_launch(void* const* d_in, const int* in_sizes, int n_in,
                              void* d_out, int out_size, void* d_ws, size_t ws_size,
                              hipStream_t stream) {
  (void)in_sizes; (void)n_in; (void)out_size;
  const float* x  = (const float*)d_in[0];
  const float* W1 = (const float*)d_in[1];
  const float* U1 = (const float*)d_in[2];
  const float* g1 = (const float*)d_in[3];
  const float* b1 = (const float*)d_in[4];
  const float* W2 = (const float*)d_in[5];
  const float* U2 = (const float*)d_in[6];
  const float* g2 = (const float*)d_in[7];
  const float* b2 = (const float*)d_in[8];

  char* ws = (char*)d_ws;
  size_t o = 0;
  auto take = [&](size_t bytes) { size_t r = o; o = (o + bytes + 255) & ~(size_t)255; return r; };
  u16* wbuf  = (u16*)(ws + take(32000ULL * 2048 * 2));   // 131 MB, reused by both layers
  u16* h1seq = (u16*)(ws + take(32000ULL * 1024 * 2));   // 65 MB layer-1 output (fp16)
  u16* xb    = (u16*)(ws + take(32000ULL * 80 * 2));
  u16* W1b   = (u16*)(ws + take(2048ULL * 80 * 2));
  u16* W2b   = (u16*)(ws + take(2048ULL * 1024 * 2));
  u16* U1b   = (u16*)(ws + take(2048ULL * 1024 * 2));
  u16* U2b   = (u16*)(ws + take(2048ULL * 1024 * 2));
  float2* ss1 = (float2*)(ws + take(2048 * 8));
  float2* ss2 = (float2*)(ws + take(2048 * 8));
  size_t zbase = o;  // everything below must start zeroed
  float* acc1 = (float*)(ws + take(2048 * 8));
  float* acc2 = (float*)(ws + take(2048 * 8));
  float* pstats1 = (float*)(ws + take(2ULL * 2 * 16 * 32 * 4 * 4));   // 32 KB
  float* pstats2 = (float*)(ws + take(2ULL * 2 * 16 * 32 * 4 * 4));
  unsigned* flags1 = (unsigned*)(ws + take(2ULL * 32 * 16 * 4));      // 4 KB
  unsigned* flags2 = (unsigned*)(ws + take(2ULL * 32 * 16 * 4));
  u16* hbuf1 = (u16*)(ws + take(32 * 1024 * 2));
  u16* hbuf2 = (u16*)(ws + take(32 * 1024 * 2));
  size_t zlen = o - zbase;
  if (ws_size < o) return;

  (void)hipMemsetAsync(ws + zbase, 0, zlen, stream);

  cvt_f32_f16<<<1280, 256, 0, stream>>>(x, xb, 32000 * 80);
  cvt_f32_f16<<<160, 256, 0, stream>>>(W1, W1b, 2048 * 80);
  cvt_f32_f16<<<1024, 256, 0, stream>>>(U1, U1b, 2048 * 1024);
  cvt_f32_f16<<<1024, 256, 0, stream>>>(W2, W2b, 2048 * 1024);
  cvt_f32_f16<<<1024, 256, 0, stream>>>(U2, U2b, 2048 * 1024);

  // ---- layer 1 ----
  gemm_f16<<<dim3(16, 250), 256, 0, stream>>>(xb, W1b, wbuf, 80);
  bn_stats<<<dim3(8, 125), 256, 0, stream>>>(wbuf, acc1);
  bn_final<<<8, 256, 0, stream>>>(acc1, g1, b1, ss1);
  rec_kernel<0><<<64, 256, 0, stream>>>(wbuf, ss1, U1b, hbuf1, pstats1, flags1, h1seq, nullptr);

  // ---- layer 2 ----
  gemm_f16<<<dim3(16, 250), 256, 0, stream>>>(h1seq, W2b, wbuf, 1024);
  bn_stats<<<dim3(8, 125), 256, 0, stream>>>(wbuf, acc2);
  bn_final<<<8, 256, 0, stream>>>(acc2, g2, b2, ss2);
  rec_kernel<1><<<64, 256, 0, stream>>>(wbuf, ss2, U2b, hbuf2, pstats2, flags2, nullptr, (float*)d_out);
}